// Round 1
// baseline (225.042 us; speedup 1.0000x reference)
//
#include <hip/hip_runtime.h>
#include <math.h>

#define NB 8
#define NA 32
#define NPAIR 496          // 32*31/2
#define TC 32              // triplets per chunk
#define TCP 36             // padded stride (float4-aligned, breaks bank pattern)
#define CUTOFF_F 3.5f
#define EPS_F 1e-7f
#define CLIP_MIN_F 1e-10f
#define PI_F 3.14159274101257324f   // float32(np.pi)

// Fused FC layer: Y[f][t] = tanh(b[f] + sum_k X[k][t]*W[k][f])  (+ R[f][t] if RES)
// Thread tile: 2 features x 4 triplets.
template<int KI, int F, bool RES>
__device__ __forceinline__ void layer_fc(
    const float* __restrict__ Wg, const float* __restrict__ bg,
    const float (* __restrict__ X)[TCP], float (* __restrict__ Y)[TCP],
    const float (* __restrict__ R)[TCP], int tid)
{
    constexpr int NF    = F / 2;        // threads along feature dim
    constexpr int NTT   = 256 / NF;     // 4-triplet tiles per pass
    constexpr int TPP   = NTT * 4;      // triplets per pass
    constexpr int NPASS = TC / TPP;
    const int fi = (tid % NF) * 2;
    const int tb = (tid / NF) * 4;
    const float bb0 = bg[fi];
    const float bb1 = bg[fi + 1];
#pragma unroll
    for (int ps = 0; ps < NPASS; ++ps) {
        const int tt = tb + ps * TPP;
        float a0[4], a1[4];
#pragma unroll
        for (int r = 0; r < 4; ++r) { a0[r] = bb0; a1[r] = bb1; }
#pragma unroll 4
        for (int k = 0; k < KI; ++k) {
            const float4 xv = *(const float4*)&X[k][tt];
            const float2 wv = *(const float2*)&Wg[k * F + fi];
            a0[0] += xv.x * wv.x; a0[1] += xv.y * wv.x;
            a0[2] += xv.z * wv.x; a0[3] += xv.w * wv.x;
            a1[0] += xv.x * wv.y; a1[1] += xv.y * wv.y;
            a1[2] += xv.z * wv.y; a1[3] += xv.w * wv.y;
        }
        float4 y0, y1;
        y0.x = tanhf(a0[0]); y0.y = tanhf(a0[1]); y0.z = tanhf(a0[2]); y0.w = tanhf(a0[3]);
        y1.x = tanhf(a1[0]); y1.y = tanhf(a1[1]); y1.z = tanhf(a1[2]); y1.w = tanhf(a1[3]);
        if (RES) {
            const float4 r0 = *(const float4*)&R[fi][tt];
            const float4 r1 = *(const float4*)&R[fi + 1][tt];
            y0.x += r0.x; y0.y += r0.y; y0.z += r0.z; y0.w += r0.w;
            y1.x += r1.x; y1.y += r1.y; y1.z += r1.z; y1.w += r1.w;
        }
        *(float4*)&Y[fi][tt]     = y0;
        *(float4*)&Y[fi + 1][tt] = y1;
    }
}

// Final layer (128 -> 256): accumulate w[t] * tanh(...) into shared GA[256].
__device__ __forceinline__ void layer_out(
    const float* __restrict__ Wg, const float* __restrict__ bg,
    const float (* __restrict__ X)[TCP], const float* __restrict__ wsh,
    float* __restrict__ GA, int tid)
{
    const int fi = (tid & 127) * 2;
    const int tb = (tid >> 7) * 4;
    const float bb0 = bg[fi];
    const float bb1 = bg[fi + 1];
#pragma unroll
    for (int ps = 0; ps < 4; ++ps) {
        const int tt = tb + ps * 8;
        float a0[4], a1[4];
#pragma unroll
        for (int r = 0; r < 4; ++r) { a0[r] = bb0; a1[r] = bb1; }
#pragma unroll 4
        for (int k = 0; k < 128; ++k) {
            const float4 xv = *(const float4*)&X[k][tt];
            const float2 wv = *(const float2*)&Wg[k * 256 + fi];
            a0[0] += xv.x * wv.x; a0[1] += xv.y * wv.x;
            a0[2] += xv.z * wv.x; a0[3] += xv.w * wv.x;
            a1[0] += xv.x * wv.y; a1[1] += xv.y * wv.y;
            a1[2] += xv.z * wv.y; a1[3] += xv.w * wv.y;
        }
        const float4 wv4 = *(const float4*)&wsh[tt];
        const float s0 = wv4.x * tanhf(a0[0]) + wv4.y * tanhf(a0[1])
                       + wv4.z * tanhf(a0[2]) + wv4.w * tanhf(a0[3]);
        const float s1 = wv4.x * tanhf(a1[0]) + wv4.y * tanhf(a1[1])
                       + wv4.z * tanhf(a1[2]) + wv4.w * tanhf(a1[3]);
        atomicAdd(&GA[fi], s0);
        atomicAdd(&GA[fi + 1], s1);
    }
}

__global__ __launch_bounds__(256) void aev_kernel(
    const float* __restrict__ D, const float* __restrict__ S,
    const float* __restrict__ W0, const float* __restrict__ b0,
    const float* __restrict__ W1, const float* __restrict__ b1,
    const float* __restrict__ W2, const float* __restrict__ b2,
    const float* __restrict__ W3, const float* __restrict__ b3,
    const float* __restrict__ W4, const float* __restrict__ b4,
    const float* __restrict__ W5, const float* __restrict__ b5,
    const float* __restrict__ W6, const float* __restrict__ b6,
    float* __restrict__ out)
{
    __shared__ __align__(16) float Dm[NA][NA];
    __shared__ float Sv[NA];
    __shared__ unsigned short prs[NPAIR];
    __shared__ int s_T;
    __shared__ __align__(16) float Xf[9][TCP];
    __shared__ __align__(16) float Bres[64][TCP];
    __shared__ __align__(16) float BA[64][TCP];
    __shared__ __align__(16) float BB[64][TCP];
    __shared__ __align__(16) float B5[128][TCP];
    __shared__ __align__(16) float wsh[TC];
    __shared__ __align__(16) float GA[256];
    __shared__ float wred[4];

    const int tid = threadIdx.x;
    const int b = blockIdx.x >> 5;
    const int i = blockIdx.x & 31;

    for (int idx = tid; idx < NA * NA; idx += 256)
        ((float*)Dm)[idx] = D[b * NA * NA + idx];
    if (tid < NA) Sv[tid] = S[b * NA + tid];
    if (tid == 0) s_T = 0;
    GA[tid] = 0.f;
    __syncthreads();

    // Build compact list of active (j,k) pairs: both legs within cutoff.
    for (int p = tid; p < NPAIR; p += 256) {
        int rem = p, j = 0;
        while (rem >= 31 - j) { rem -= 31 - j; ++j; }
        const int k = j + 1 + rem;
        const float dij = Dm[i][j];
        const float dik = Dm[i][k];
        if (dij < CUTOFF_F && dij != 0.f && dik < CUTOFF_F && dik != 0.f) {
            const int x = atomicAdd(&s_T, 1);
            prs[x] = (unsigned short)(j | (k << 8));
        }
    }
    __syncthreads();
    const int T = s_T;

    for (int t0 = 0; t0 < T; t0 += TC) {
        // ---- features for this chunk (pad inactive slots with 0, w=0) ----
        if (tid < TC) {
            float f9[9];
#pragma unroll
            for (int q = 0; q < 9; ++q) f9[q] = 0.f;
            float w = 0.f;
            const int t = t0 + tid;
            if (t < T) {
                const int jk = prs[t];
                const int j = jk & 255;
                const int k = jk >> 8;
                const float Rij = Dm[i][j], Rik = Dm[i][k], Rjk = Dm[j][k];
                const float zi = Sv[i], zj = Sv[j], zk = Sv[k];
                const float ci = (Rij*Rij + Rik*Rik - Rjk*Rjk) / fmaxf(2.f*Rij*Rik, CLIP_MIN_F);
                const float cj = (Rij*Rij + Rjk*Rjk - Rik*Rik) / fmaxf(2.f*Rij*Rjk, CLIP_MIN_F);
                const float ck = (Rik*Rik + Rjk*Rjk - Rij*Rij) / fmaxf(2.f*Rik*Rjk, CLIP_MIN_F);
                float g0 = Rij + Rik + Rjk;
                float g1 = Rij*Rik + Rij*Rjk + Rik*Rjk;
                float g2 = Rij*Rik*Rjk;
                const float gn = sqrtf(g0*g0 + g1*g1 + g2*g2) + EPS_F;
                g0 /= gn; g1 /= gn; g2 /= gn;
                float h0 = zi + zj + zk;
                float h1 = ci + cj + ck;
                float h2 = zi*(zj + zk) + zj*zk - ci*(cj + ck) - cj*ck;
                float h3 = zi*(cj + ck) + ci*(zj + zk) + zj*ck + cj*zk;
                float h4 = zi*(zj*zk - cj*ck) - ci*(zj*ck + cj*zk);
                float h5 = zi*(zj*ck + cj*zk) + ci*(zj*zk - cj*ck);
                const float hn = sqrtf(h0*h0 + h1*h1 + h2*h2 + h3*h3 + h4*h4 + h5*h5) + EPS_F;
                h0 /= hn; h1 /= hn; h2 /= hn; h3 /= hn; h4 /= hn; h5 /= hn;
                f9[0] = g0; f9[1] = g1; f9[2] = g2;
                f9[3] = h0; f9[4] = h1; f9[5] = h2; f9[6] = h3; f9[7] = h4; f9[8] = h5;
                const float fcij = 0.5f * cosf(PI_F * Rij / CUTOFF_F) + 0.5f;
                const float fcik = 0.5f * cosf(PI_F * Rik / CUTOFF_F) + 0.5f;
                w = fcij * fcik;
            }
#pragma unroll
            for (int q = 0; q < 9; ++q) Xf[q][tid] = f9[q];
            wsh[tid] = w;
        }
        __syncthreads();

        layer_fc<9,  64, false>(W0, b0, Xf,   Bres, nullptr, tid); __syncthreads();
        layer_fc<64, 64, true >(W1, b1, Bres, BA,   Bres,   tid);  __syncthreads(); // xb1
        layer_fc<64, 64, false>(W2, b2, BA,   BB,   nullptr, tid); __syncthreads(); // x2
        layer_fc<64, 64, false>(W3, b3, BB,   Bres, nullptr, tid); __syncthreads(); // x3
        layer_fc<64, 64, true >(W4, b4, Bres, BB,   BA,     tid);  __syncthreads(); // xb2
        layer_fc<64, 128,false>(W5, b5, BB,   B5,   nullptr, tid); __syncthreads(); // xb3
        layer_out(W6, b6, B5, wsh, GA, tid);
        __syncthreads();
    }

    __syncthreads();
    const float v = GA[tid];
    float ss = v * v;
#pragma unroll
    for (int off = 32; off > 0; off >>= 1) ss += __shfl_down(ss, off);
    if ((tid & 63) == 0) wred[tid >> 6] = ss;
    __syncthreads();
    const float tot = wred[0] + wred[1] + wred[2] + wred[3];
    out[blockIdx.x * 256 + tid] = v / (sqrtf(tot) + EPS_F);
}

extern "C" void kernel_launch(void* const* d_in, const int* in_sizes, int n_in,
                              void* d_out, int out_size, void* d_ws, size_t ws_size,
                              hipStream_t stream)
{
    const float* D  = (const float*)d_in[0];
    const float* S  = (const float*)d_in[1];
    const float* W0 = (const float*)d_in[2];  const float* b0 = (const float*)d_in[3];
    const float* W1 = (const float*)d_in[4];  const float* b1 = (const float*)d_in[5];
    const float* W2 = (const float*)d_in[6];  const float* b2 = (const float*)d_in[7];
    const float* W3 = (const float*)d_in[8];  const float* b3 = (const float*)d_in[9];
    const float* W4 = (const float*)d_in[10]; const float* b4 = (const float*)d_in[11];
    const float* W5 = (const float*)d_in[12]; const float* b5 = (const float*)d_in[13];
    const float* W6 = (const float*)d_in[14]; const float* b6 = (const float*)d_in[15];
    float* out = (float*)d_out;

    aev_kernel<<<dim3(NB * NA), dim3(256), 0, stream>>>(
        D, S, W0, b0, W1, b1, W2, b2, W3, b3, W4, b4, W5, b5, W6, b6, out);
}

// Round 2
// 134.620 us; speedup vs baseline: 1.6717x; 1.6717x over previous
//
#include <hip/hip_runtime.h>
#include <math.h>

#define NB 8
#define NA 32
#define NCELL 256
#define NPAIR 496
#define SLOT 496          // max triplets per cell (hard upper bound)
#define FST 10            // 9 features + weight
#define TC 16             // triplets per chunk
#define XS 20             // padded row stride for activation buffers (floats)
#define NQ 8              // chunk-slots per cell (grid split)
#define CUTOFF_F 3.5f
#define EPS_F 1e-7f
#define CLIP_MIN_F 1e-10f
#define PI_F 3.14159274101257324f   // float32(np.pi)

// ---------------- K1: compact active triplets, compute features ----------------
__global__ __launch_bounds__(256) void aev_feat(
    const float* __restrict__ D, const float* __restrict__ S,
    float* __restrict__ feat, int* __restrict__ count, float* __restrict__ GA)
{
    __shared__ float Dm[NA][NA];
    __shared__ float Sv[NA];
    __shared__ int s_T;
    const int tid = threadIdx.x;
    const int cell = blockIdx.x;
    const int b = cell >> 5, i = cell & 31;

    for (int idx = tid; idx < NA * NA; idx += 256)
        ((float*)Dm)[idx] = D[b * NA * NA + idx];
    if (tid < NA) Sv[tid] = S[b * NA + tid];
    if (tid == 0) s_T = 0;
    GA[cell * 256 + tid] = 0.f;      // zero global accumulator (ws is poisoned)
    __syncthreads();

    for (int p = tid; p < NPAIR; p += 256) {
        int rem = p, j = 0;
        while (rem >= 31 - j) { rem -= 31 - j; ++j; }
        const int k = j + 1 + rem;
        const float dij = Dm[i][j], dik = Dm[i][k];
        if (dij < CUTOFF_F && dij != 0.f && dik < CUTOFF_F && dik != 0.f) {
            const int slot = atomicAdd(&s_T, 1);
            const float Rij = dij, Rik = dik, Rjk = Dm[j][k];
            const float zi = Sv[i], zj = Sv[j], zk = Sv[k];
            const float ci = (Rij*Rij + Rik*Rik - Rjk*Rjk) / fmaxf(2.f*Rij*Rik, CLIP_MIN_F);
            const float cj = (Rij*Rij + Rjk*Rjk - Rik*Rik) / fmaxf(2.f*Rij*Rjk, CLIP_MIN_F);
            const float ck = (Rik*Rik + Rjk*Rjk - Rij*Rij) / fmaxf(2.f*Rik*Rjk, CLIP_MIN_F);
            float g0 = Rij + Rik + Rjk;
            float g1 = Rij*Rik + Rij*Rjk + Rik*Rjk;
            float g2 = Rij*Rik*Rjk;
            const float gn = sqrtf(g0*g0 + g1*g1 + g2*g2) + EPS_F;
            float h0 = zi + zj + zk;
            float h1 = ci + cj + ck;
            float h2 = zi*(zj + zk) + zj*zk - ci*(cj + ck) - cj*ck;
            float h3 = zi*(cj + ck) + ci*(zj + zk) + zj*ck + cj*zk;
            float h4 = zi*(zj*zk - cj*ck) - ci*(zj*ck + cj*zk);
            float h5 = zi*(zj*ck + cj*zk) + ci*(zj*zk - cj*ck);
            const float hn = sqrtf(h0*h0 + h1*h1 + h2*h2 + h3*h3 + h4*h4 + h5*h5) + EPS_F;
            const float fcij = 0.5f * cosf(PI_F * Rij / CUTOFF_F) + 0.5f;
            const float fcik = 0.5f * cosf(PI_F * Rik / CUTOFF_F) + 0.5f;
            float* fp = &feat[(cell * SLOT + slot) * FST];
            fp[0] = g0 / gn; fp[1] = g1 / gn; fp[2] = g2 / gn;
            fp[3] = h0 / hn; fp[4] = h1 / hn; fp[5] = h2 / hn;
            fp[6] = h3 / hn; fp[7] = h4 / hn; fp[8] = h5 / hn;
            fp[9] = fcij * fcik;
        }
    }
    __syncthreads();
    if (tid == 0) count[cell] = s_T;
}

// ---------------- K2 layers ----------------
// 64-output layer, weights staged in LDS. Thread = 1 feature x 4 triplets.
template<int K, bool RES>
__device__ __forceinline__ void layer64(
    const float* __restrict__ Wg, const float* __restrict__ bg,
    float* __restrict__ Wl,
    const float* __restrict__ X, float* __restrict__ Y,
    const float* __restrict__ R, int tid)
{
    for (int idx = tid * 4; idx < K * 64; idx += 1024)
        *(float4*)&Wl[idx] = *(const float4*)&Wg[idx];
    __syncthreads();
    const int fi = tid & 63;
    const int xo = (tid >> 6) * 4;
    float a0 = bg[fi], a1 = a0, a2 = a0, a3 = a0;
#pragma unroll 4
    for (int k = 0; k < K; ++k) {
        const float4 xv = *(const float4*)&X[k * XS + xo];   // wave-broadcast
        const float w = Wl[k * 64 + fi];
        a0 += xv.x * w; a1 += xv.y * w; a2 += xv.z * w; a3 += xv.w * w;
    }
    float4 y;
    y.x = tanhf(a0); y.y = tanhf(a1); y.z = tanhf(a2); y.w = tanhf(a3);
    if (RES) {
        const float4 r = *(const float4*)&R[fi * XS + xo];
        y.x += r.x; y.y += r.y; y.z += r.z; y.w += r.w;
    }
    *(float4*)&Y[fi * XS + xo] = y;
    __syncthreads();
}

// 64 -> 128 layer, weights direct from global (L2). Thread = 2 features x 4 triplets.
__device__ __forceinline__ void layer5f(
    const float* __restrict__ W5, const float* __restrict__ b5,
    const float* __restrict__ X, float* __restrict__ Y, int tid)
{
    const int fo = (tid & 63) * 2;
    const int xo = (tid >> 6) * 4;
    const float2 bb = *(const float2*)&b5[fo];
    float a0[4], a1[4];
#pragma unroll
    for (int r = 0; r < 4; ++r) { a0[r] = bb.x; a1[r] = bb.y; }
#pragma unroll 4
    for (int k = 0; k < 64; ++k) {
        const float4 xv = *(const float4*)&X[k * XS + xo];
        const float2 wv = *(const float2*)&W5[k * 128 + fo];
        a0[0] += xv.x * wv.x; a0[1] += xv.y * wv.x; a0[2] += xv.z * wv.x; a0[3] += xv.w * wv.x;
        a1[0] += xv.x * wv.y; a1[1] += xv.y * wv.y; a1[2] += xv.z * wv.y; a1[3] += xv.w * wv.y;
    }
    float4 y0, y1;
    y0.x = tanhf(a0[0]); y0.y = tanhf(a0[1]); y0.z = tanhf(a0[2]); y0.w = tanhf(a0[3]);
    y1.x = tanhf(a1[0]); y1.y = tanhf(a1[1]); y1.z = tanhf(a1[2]); y1.w = tanhf(a1[3]);
    *(float4*)&Y[fo * XS + xo] = y0;
    *(float4*)&Y[(fo + 1) * XS + xo] = y1;
    __syncthreads();
}

// 128 -> 256 final layer, weights direct; accumulate w*tanh into LDS GAacc.
__device__ __forceinline__ void layer6f(
    const float* __restrict__ W6, const float* __restrict__ b6,
    const float* __restrict__ X, const float* __restrict__ wsh,
    float* __restrict__ GAacc, int tid)
{
    const int fo = (tid & 127) * 2;
    const int xo = (tid >> 7) * 8;       // 2 halves x 8 triplets
    const float2 bb = *(const float2*)&b6[fo];
    float a0[8], a1[8];
#pragma unroll
    for (int r = 0; r < 8; ++r) { a0[r] = bb.x; a1[r] = bb.y; }
#pragma unroll 2
    for (int k = 0; k < 128; ++k) {
        const float4 xv0 = *(const float4*)&X[k * XS + xo];
        const float4 xv1 = *(const float4*)&X[k * XS + xo + 4];
        const float2 wv = *(const float2*)&W6[k * 256 + fo];
        a0[0] += xv0.x * wv.x; a0[1] += xv0.y * wv.x; a0[2] += xv0.z * wv.x; a0[3] += xv0.w * wv.x;
        a0[4] += xv1.x * wv.x; a0[5] += xv1.y * wv.x; a0[6] += xv1.z * wv.x; a0[7] += xv1.w * wv.x;
        a1[0] += xv0.x * wv.y; a1[1] += xv0.y * wv.y; a1[2] += xv0.z * wv.y; a1[3] += xv0.w * wv.y;
        a1[4] += xv1.x * wv.y; a1[5] += xv1.y * wv.y; a1[6] += xv1.z * wv.y; a1[7] += xv1.w * wv.y;
    }
    float s0 = 0.f, s1 = 0.f;
#pragma unroll
    for (int r = 0; r < 8; ++r) {
        const float wt = wsh[xo + r];
        s0 += wt * tanhf(a0[r]);
        s1 += wt * tanhf(a1[r]);
    }
    atomicAdd(&GAacc[fo], s0);
    atomicAdd(&GAacc[fo + 1], s1);
    __syncthreads();
}

// ---------------- K2: MLP over chunk-slots ----------------
__global__ __launch_bounds__(256) void aev_mlp(
    const float* __restrict__ feat, const int* __restrict__ count,
    const float* __restrict__ W0, const float* __restrict__ b0,
    const float* __restrict__ W1, const float* __restrict__ b1,
    const float* __restrict__ W2, const float* __restrict__ b2,
    const float* __restrict__ W3, const float* __restrict__ b3,
    const float* __restrict__ W4, const float* __restrict__ b4,
    const float* __restrict__ W5, const float* __restrict__ b5,
    const float* __restrict__ W6, const float* __restrict__ b6,
    float* __restrict__ GA)
{
    __shared__ __align__(16) float Xs[9 * XS];
    __shared__ float wsh[TC];
    __shared__ __align__(16) float U0[64 * XS];
    __shared__ __align__(16) float U1[64 * XS];
    __shared__ __align__(16) float U2[64 * XS];
    __shared__ __align__(16) float U3[128 * XS];
    __shared__ __align__(16) float Wl[64 * 64];
    __shared__ float GAacc[256];

    const int tid = threadIdx.x;
    const int cell = blockIdx.x & 255;
    const int q = blockIdx.x >> 8;
    const int T = count[cell];
    const int nch = (T + TC - 1) / TC;
    if (q >= nch) return;

    GAacc[tid] = 0.f;

    for (int c = q; c < nch; c += NQ) {
        const int t0 = c * TC;
        if (tid < TC * FST) {
            const int t = tid / FST, qf = tid % FST;
            const int slot = t0 + t;
            const float v = (slot < T) ? feat[(cell * SLOT + slot) * FST + qf] : 0.f;
            if (qf == 9) wsh[t] = v; else Xs[qf * XS + t] = v;
        }
        __syncthreads();

        layer64<9,  false>(W0, b0, Wl, Xs, U0, nullptr, tid);   // x_res
        layer64<64, true >(W1, b1, Wl, U0, U1, U0, tid);        // xb1 = tanh(.)+x_res
        layer64<64, false>(W2, b2, Wl, U1, U2, nullptr, tid);   // x2
        layer64<64, false>(W3, b3, Wl, U2, U3, nullptr, tid);   // x3 (rows 0-63 of U3)
        layer64<64, true >(W4, b4, Wl, U3, U2, U1, tid);        // xb2 = tanh(.)+xb1
        layer5f(W5, b5, U2, U3, tid);                           // xb3 (128)
        layer6f(W6, b6, U3, wsh, GAacc, tid);                   // accumulate
    }

    atomicAdd(&GA[cell * 256 + tid], GAacc[tid]);
}

// ---------------- K3: normalize ----------------
__global__ __launch_bounds__(256) void aev_norm(
    const float* __restrict__ GA, float* __restrict__ out)
{
    __shared__ float wred[4];
    const int tid = threadIdx.x;
    const int cell = blockIdx.x;
    const float v = GA[cell * 256 + tid];
    float ss = v * v;
#pragma unroll
    for (int off = 32; off > 0; off >>= 1) ss += __shfl_down(ss, off);
    if ((tid & 63) == 0) wred[tid >> 6] = ss;
    __syncthreads();
    const float tot = wred[0] + wred[1] + wred[2] + wred[3];
    out[cell * 256 + tid] = v / (sqrtf(tot) + EPS_F);
}

extern "C" void kernel_launch(void* const* d_in, const int* in_sizes, int n_in,
                              void* d_out, int out_size, void* d_ws, size_t ws_size,
                              hipStream_t stream)
{
    const float* D  = (const float*)d_in[0];
    const float* S  = (const float*)d_in[1];
    const float* W0 = (const float*)d_in[2];  const float* b0 = (const float*)d_in[3];
    const float* W1 = (const float*)d_in[4];  const float* b1 = (const float*)d_in[5];
    const float* W2 = (const float*)d_in[6];  const float* b2 = (const float*)d_in[7];
    const float* W3 = (const float*)d_in[8];  const float* b3 = (const float*)d_in[9];
    const float* W4 = (const float*)d_in[10]; const float* b4 = (const float*)d_in[11];
    const float* W5 = (const float*)d_in[12]; const float* b5 = (const float*)d_in[13];
    const float* W6 = (const float*)d_in[14]; const float* b6 = (const float*)d_in[15];
    float* out = (float*)d_out;

    float* feat  = (float*)d_ws;                        // 256*496*10 floats
    int*   count = (int*)(feat + NCELL * SLOT * FST);   // 256 ints
    float* GA    = (float*)(count + 256);               // 256*256 floats

    aev_feat<<<dim3(NCELL), dim3(256), 0, stream>>>(D, S, feat, count, GA);
    aev_mlp<<<dim3(NCELL * NQ), dim3(256), 0, stream>>>(
        feat, count, W0, b0, W1, b1, W2, b2, W3, b3, W4, b4, W5, b5, W6, b6, GA);
    aev_norm<<<dim3(NCELL), dim3(256), 0, stream>>>(GA, out);
}